// Round 18
// baseline (1638.827 us; speedup 1.0000x reference)
//
#include <hip/hip_runtime.h>

#define N_ROWS 131072
#define DIM    128
#define QST    4
#define KC     1024
#define BM     128     // rows per workgroup (4 waves x 32 rows)
#define NTH    256
#define PNTH   256
#define NWAVE  4
#define NCHUNK 64      // 16 codes per chunk, 8 KB fragments
#define EPS    6e-3f   // certified fp16-split argmin margin
#define FLAGB  (1 << 16)

typedef _Float16 h8  __attribute__((ext_vector_type(8)));
typedef float    fx4 __attribute__((ext_vector_type(4)));

typedef __attribute__((address_space(3))) void lds_void;
typedef const __attribute__((address_space(1))) void glb_void;

#define MFMA16(a, b, c) __builtin_amdgcn_mfma_f32_16x16x32_f16((a), (b), (c), 0, 0, 0)

// packB halfs layout: [q][ch(64)][kt(4)][hl(2)][lane(64)][j(8)]
__global__ void k_prep(const float* __restrict__ cb,
                       double* __restrict__ cvec64, float* __restrict__ cvec32,
                       _Float16* __restrict__ packB) {
  int gid = blockIdx.x * blockDim.x + threadIdx.x;
  if (gid >= QST * KC) return;
  int q = gid >> 10, code = gid & (KC - 1);
  int ch = code >> 4, n = code & 15;
  const float* e = cb + ((size_t)q * KC + code) * DIM;
  double s = 0.0;
  for (int d = 0; d < DIM; d++) {
    float v = e[d];
    s = fma((double)v, (double)v, s);
    int kt = d >> 5, g = (d >> 3) & 3, j = d & 7;
    int lane = g * 16 + n;
    size_t base = ((size_t)q * NCHUNK + ch) * 4096 + (size_t)kt * 1024 + lane * 8 + j;
    _Float16 hh = (_Float16)v;
    packB[base]       = hh;                          // hi
    packB[base + 512] = (_Float16)(v - (float)hh);   // lo
  }
  cvec64[q * KC + code] = s;
  cvec32[q * KC + code] = (float)s;
}

// ALL 4 STAGES FUSED. The residual state lives ONLY in registers as the
// fp16 hi/lo split (ah+al reconstructs r to ~1e-6 abs; R2 anchor: real top-2
// gaps >~1e-3, so this cannot flip argmins). Update: r_new = (ah+al) - E[idx],
// re-split in registers. r never touches global memory; x_q = x - r at st=3.
__global__ __launch_bounds__(NTH, 4) void k_fused(
    const float* __restrict__ x, float* xq,
    const float* __restrict__ cb,
    const double* __restrict__ cvec64, const float* __restrict__ cvec32,
    const _Float16* __restrict__ packB,
    float* oidx, float* __restrict__ lpart)
{
  __shared__ _Float16 Bl[3 * 4096];   // ring-3 of 8 KB chunks = 24 KB
  __shared__ float    cvecL[KC];      // 4 KB
  __shared__ int      idxsW[BM];      // working idx (+flag bit16)
  __shared__ float    rowbuf[DIM];    // rescue row broadcast
  __shared__ double   redd[NWAVE];
  __shared__ int      redi[NWAVE];
  __shared__ float    redf[NWAVE];
  __shared__ int      flags[NWAVE];

  const int tid = threadIdx.x;
  const int lane = tid & 63, wv = tid >> 6;
  const int tx = lane & 15;
  const size_t rowbase = (size_t)blockIdx.x * BM;

  // ---- prologue: A-fragments of x (2 rowtiles x 4 ktiles, fp16 hi/lo)
  h8 ah[2][4], al[2][4];
  #pragma unroll
  for (int rt = 0; rt < 2; rt++) {
    const float* rowp = x + (rowbase + wv * 32 + rt * 16 + (lane & 15)) * (size_t)DIM
                        + ((lane >> 4) * 8);
    #pragma unroll
    for (int kt = 0; kt < 4; kt++) {
      float4 f0 = *(const float4*)(rowp + kt * 32);
      float4 f1 = *(const float4*)(rowp + kt * 32 + 4);
      float vv[8] = {f0.x, f0.y, f0.z, f0.w, f1.x, f1.y, f1.z, f1.w};
      #pragma unroll
      for (int j = 0; j < 8; j++) {
        _Float16 hh = (_Float16)vv[j];
        ah[rt][kt][j] = hh;
        al[rt][kt][j] = (_Float16)(vv[j] - (float)hh);
      }
    }
  }

  float lsum = 0.f;
  const fx4 zero4 = {0.f, 0.f, 0.f, 0.f};

  #pragma unroll 1
  for (int st = 0; st < QST; st++) {
    const _Float16* PBq  = packB + (size_t)st * 262144;
    const float*    cq32 = cvec32 + st * KC;
    const double*   cq64 = cvec64 + st * KC;
    const float*    Eq   = cb + (size_t)st * KC * DIM;

    __syncthreads();   // prior stage quiesced (LDS reads done, vmcnt drained)
    for (int i = tid; i < KC; i += NTH) cvecL[i] = cq32[i];
    __syncthreads();   // cvecL visible; drains all preceding VMEM (vmcnt->0)

    // ---- main loop: VERBATIM round-13 structure (ring-3, counted vmcnt(2))
    auto stageB = [&](int ch, int buf) {
      const _Float16* src = PBq + (size_t)ch * 4096 + wv * 1024 + lane * 8;
      _Float16* dst = Bl + (size_t)buf * 4096 + wv * 1024;   // wave-uniform base
      #pragma unroll
      for (int i = 0; i < 2; i++)
        __builtin_amdgcn_global_load_lds((glb_void*)(src + i * 512),
                                         (lds_void*)(dst + i * 512), 16, 0, 0);
    };

    float b1[8], b2[8];
    int   i1[8];
    #pragma unroll
    for (int i = 0; i < 8; i++) { b1[i] = 3.4e38f; b2[i] = 3.4e38f; i1[i] = 0; }

    fx4 accPrev[2];
    accPrev[0] = zero4; accPrev[1] = zero4;

    stageB(0, 0); stageB(1, 1);

    int buf = 0, bufStage = 2;   // buf = ch%3, bufStage = (ch+2)%3
    #pragma unroll 1
    for (int ch = 0; ch < NCHUNK; ch++) {
      if (ch < NCHUNK - 1) asm volatile("s_waitcnt vmcnt(2)" ::: "memory");
      else                 asm volatile("s_waitcnt vmcnt(0)" ::: "memory");
      __builtin_amdgcn_s_barrier();     // all waves' ch-loads visible; buf (ch-1)%3 retired
      asm volatile("" ::: "memory");    // pin the stage below the barrier
      if (ch + 2 < NCHUNK) stageB(ch + 2, bufStage);

      // deferred score of chunk ch-1 (register-only)
      if (ch > 0) {
        int code = (ch - 1) * 16 + tx;
        float cvv = cvecL[code];
        #pragma unroll
        for (int rt = 0; rt < 2; rt++) {
          #pragma unroll
          for (int j = 0; j < 4; j++) {
            float sc = fmaf(-2.f, accPrev[rt][j], cvv);
            int r = rt * 4 + j;
            if (sc < b1[r]) { b2[r] = b1[r]; b1[r] = sc; i1[r] = code; }
            else            { b2[r] = fminf(b2[r], sc); }
          }
        }
      }

      const _Float16* Bb = Bl + (size_t)buf * 4096;
      fx4 acc[2];
      acc[0] = zero4; acc[1] = zero4;

      __builtin_amdgcn_s_setprio(1);
      #pragma unroll
      for (int kt = 0; kt < 4; kt++) {
        const _Float16* p = Bb + (size_t)kt * 1024 + lane * 8;
        h8 bh = *(const h8*)p;
        h8 bl = *(const h8*)(p + 512);
        #pragma unroll
        for (int rt = 0; rt < 2; rt++) {
          acc[rt] = MFMA16(ah[rt][kt], bh, acc[rt]);
          acc[rt] = MFMA16(al[rt][kt], bh, acc[rt]);
          acc[rt] = MFMA16(ah[rt][kt], bl, acc[rt]);
        }
      }
      __builtin_amdgcn_s_setprio(0);

      accPrev[0] = acc[0];
      accPrev[1] = acc[1];

      buf = (buf == 2) ? 0 : buf + 1;
      bufStage = (bufStage == 2) ? 0 : bufStage + 1;
    }

    // tail score
    {
      int code = (NCHUNK - 1) * 16 + tx;
      float cvv = cvecL[code];
      #pragma unroll
      for (int rt = 0; rt < 2; rt++) {
        #pragma unroll
        for (int j = 0; j < 4; j++) {
          float sc = fmaf(-2.f, accPrev[rt][j], cvv);
          int r = rt * 4 + j;
          if (sc < b1[r]) { b2[r] = b1[r]; b1[r] = sc; i1[r] = code; }
          else            { b2[r] = fminf(b2[r], sc); }
        }
      }
    }

    // ---- cross-lane top-2 reduce over the 16 lanes sharing each row
    #pragma unroll
    for (int m = 1; m < 16; m <<= 1) {
      #pragma unroll
      for (int r = 0; r < 8; r++) {
        float ob1 = __shfl_xor(b1[r], m, 64);
        int   oi1 = __shfl_xor(i1[r], m, 64);
        float ob2 = __shfl_xor(b2[r], m, 64);
        bool take = (ob1 < b1[r]) || (ob1 == b1[r] && oi1 < i1[r]);
        float loser = take ? b1[r] : ob1;
        if (take) { b1[r] = ob1; i1[r] = oi1; }
        b2[r] = fminf(fminf(b2[r], ob2), loser);
      }
    }

    if (tx == 0) {
      int g = lane >> 4;
      #pragma unroll
      for (int rt = 0; rt < 2; rt++)
        #pragma unroll
        for (int j = 0; j < 4; j++) {
          int r = rt * 4 + j;
          int fl = (b2[r] - b1[r] <= EPS) ? FLAGB : 0;
          idxsW[wv * 32 + rt * 16 + g * 4 + j] = i1[r] | fl;
        }
    }
    __syncthreads();

    // ---- exact fp64 rescue (rare): row vector = registers' (ah+al), the very
    //      residual the MFMAs scored, broadcast via LDS by its owner lanes
    {
      bool pred = (tid < BM) && (idxsW[tid] & FLAGB);
      unsigned long long bal = __ballot(pred);
      if (lane == 0) flags[wv] = (bal != 0ull) ? 1 : 0;
    }
    __syncthreads();
    int anyflag = flags[0] | flags[1] | flags[2] | flags[3];
    if (anyflag) {
      for (int row = 0; row < BM; row++) {
        if (!(idxsW[row] & FLAGB)) continue;       // uniform branch
        if ((row >> 5) == wv && (lane & 15) == (row & 15)) {
          int rt = (row >> 4) & 1;
          int d0b = (lane >> 4) * 8;
          #pragma unroll
          for (int kt = 0; kt < 4; kt++)
            #pragma unroll
            for (int j = 0; j < 8; j++)
              rowbuf[d0b + kt * 32 + j] = (float)ah[rt][kt][j] + (float)al[rt][kt][j];
        }
        __syncthreads();
        double dot[4] = {0.0, 0.0, 0.0, 0.0};
        for (int d = 0; d < DIM; d++) {
          double a = (double)rowbuf[d];            // LDS broadcast
          #pragma unroll
          for (int c = 0; c < 4; c++)
            dot[c] = fma(a, (double)Eq[(size_t)(tid + c * NTH) * DIM + d], dot[c]);
        }
        double bs = 1e300; int bk = 0;
        #pragma unroll
        for (int c = 0; c < 4; c++) {
          int k = tid + c * NTH;
          double s = fma(-2.0, dot[c], cq64[k]);
          if (s < bs || (s == bs && k < bk)) { bs = s; bk = k; }
        }
        #pragma unroll
        for (int m = 1; m < 64; m <<= 1) {
          double ob = __shfl_xor(bs, m, 64);
          int    ok = __shfl_xor(bk, m, 64);
          if (ob < bs || (ob == bs && ok < bk)) { bs = ob; bk = ok; }
        }
        if (lane == 0) { redd[wv] = bs; redi[wv] = bk; }
        __syncthreads();
        if (tid == 0) {
          double fb = redd[0]; int fk = redi[0];
          #pragma unroll
          for (int w = 1; w < NWAVE; w++) {
            if (redd[w] < fb || (redd[w] == fb && redi[w] < fk)) { fb = redd[w]; fk = redi[w]; }
          }
          idxsW[row] = fk;                         // flag cleared
        }
        __syncthreads();
      }
    }

    // ---- finalize indices for this stage
    if (tid < BM) oidx[(rowbase + tid) * 4 + st] = (float)(idxsW[tid] & 1023);
    __syncthreads();

    // ---- register-local update: r_new = (ah+al) - E[idx]; loss += r_new^2;
    //      st<3 -> re-split into ah/al; st==3 -> x_q = x - r_new
    #pragma unroll
    for (int rt = 0; rt < 2; rt++) {
      int row = wv * 32 + rt * 16 + (lane & 15);
      int kidx = idxsW[row] & 1023;
      int d0b = (lane >> 4) * 8;
      #pragma unroll
      for (int kt = 0; kt < 4; kt++) {
        int d0 = d0b + kt * 32;
        const float* ep = Eq + (size_t)kidx * DIM + d0;
        float4 e0 = *(const float4*)(ep);
        float4 e1 = *(const float4*)(ep + 4);
        float e8[8] = {e0.x, e0.y, e0.z, e0.w, e1.x, e1.y, e1.z, e1.w};
        float r8[8];
        #pragma unroll
        for (int j = 0; j < 8; j++) {
          r8[j] = ((float)ah[rt][kt][j] + (float)al[rt][kt][j]) - e8[j];
          lsum = fmaf(r8[j], r8[j], lsum);
        }
        if (st < QST - 1) {
          #pragma unroll
          for (int j = 0; j < 8; j++) {
            _Float16 hh = (_Float16)r8[j];
            ah[rt][kt][j] = hh;
            al[rt][kt][j] = (_Float16)(r8[j] - (float)hh);
          }
        } else {
          const float* xp = x + (rowbase + row) * (size_t)DIM + d0;
          float4 xf0 = *(const float4*)(xp);
          float4 xf1 = *(const float4*)(xp + 4);
          float* op = xq + (rowbase + row) * (size_t)DIM + d0;
          *(float4*)(op)     = make_float4(xf0.x - r8[0], xf0.y - r8[1],
                                           xf0.z - r8[2], xf0.w - r8[3]);
          *(float4*)(op + 4) = make_float4(xf1.x - r8[4], xf1.y - r8[5],
                                           xf1.z - r8[6], xf1.w - r8[7]);
        }
      }
    }
  }

  // ---- block loss reduce -> lpart[block]
  #pragma unroll
  for (int m = 1; m < 64; m <<= 1) lsum += __shfl_xor(lsum, m, 64);
  if (lane == 0) redf[wv] = lsum;
  __syncthreads();
  if (tid == 0) lpart[blockIdx.x] = redf[0] + redf[1] + redf[2] + redf[3];
}

__global__ void k_loss(const float* __restrict__ part, float* __restrict__ o) {
  __shared__ float red[4];
  int tid = threadIdx.x;
  float s = 0.f;
  for (int i = tid; i < N_ROWS / BM; i += PNTH) s += part[i];
  #pragma unroll
  for (int m = 1; m < 64; m <<= 1) s += __shfl_xor(s, m, 64);
  if ((tid & 63) == 0) red[tid >> 6] = s;
  __syncthreads();
  if (tid == 0)
    o[0] = (red[0] + red[1] + red[2] + red[3]) *
           (1.25f / ((float)QST * (float)N_ROWS * (float)DIM));
}

extern "C" void kernel_launch(void* const* d_in, const int* in_sizes, int n_in,
                              void* d_out, int out_size, void* d_ws, size_t ws_size,
                              hipStream_t stream) {
  const float* x  = (const float*)d_in[0];
  const float* cb = (const float*)d_in[1];
  float* out = (float*)d_out;
  float* ws  = (float*)d_ws;

  double*   cvec64 = (double*)ws;                           // Q*K fp64 ||E||^2
  float*    cvec32 = (float*)(cvec64 + (size_t)QST * KC);
  float*    part   = cvec32 + (size_t)QST * KC;             // 1024 loss partials
  _Float16* packB  = (_Float16*)(part + (size_t)(N_ROWS / BM)); // 2 MB frags

  float* out_loss = out + (size_t)N_ROWS * DIM;
  float* out_idx  = out_loss + 1;

  k_prep<<<(QST * KC + PNTH - 1) / PNTH, PNTH, 0, stream>>>(cb, cvec64, cvec32, packB);

  k_fused<<<N_ROWS / BM, NTH, 0, stream>>>(x, out, cb, cvec64, cvec32, packB,
                                           out_idx, part);

  k_loss<<<1, PNTH, 0, stream>>>(part, out_loss);
}

// Round 19
// 721.592 us; speedup vs baseline: 2.2711x; 2.2711x over previous
//
#include <hip/hip_runtime.h>

#define N_ROWS 131072
#define DIM    128
#define QST    4
#define KC     1024
#define BM     128     // rows per workgroup (4 waves x 32 rows)
#define NTH    256
#define PNTH   256
#define NWAVE  4
#define NCHUNK 64      // 16 codes per chunk, 8 KB fragments
#define EPS    6e-3f   // certified fp16-split argmin margin
#define FLAGB  (1 << 16)

typedef _Float16 h8  __attribute__((ext_vector_type(8)));
typedef float    fx4 __attribute__((ext_vector_type(4)));

typedef __attribute__((address_space(3))) void lds_void;
typedef const __attribute__((address_space(1))) void glb_void;

#define MFMA16(a, b, c) __builtin_amdgcn_mfma_f32_16x16x32_f16((a), (b), (c), 0, 0, 0)

// packB halfs layout: [q][ch(64)][kt(4)][hl(2)][lane(64)][j(8)]
__global__ void k_prep(const float* __restrict__ cb,
                       double* __restrict__ cvec64, float* __restrict__ cvec32,
                       _Float16* __restrict__ packB) {
  int gid = blockIdx.x * blockDim.x + threadIdx.x;
  if (gid >= QST * KC) return;
  int q = gid >> 10, code = gid & (KC - 1);
  int ch = code >> 4, n = code & 15;
  const float* e = cb + ((size_t)q * KC + code) * DIM;
  double s = 0.0;
  for (int d = 0; d < DIM; d++) {
    float v = e[d];
    s = fma((double)v, (double)v, s);
    int kt = d >> 5, g = (d >> 3) & 3, j = d & 7;
    int lane = g * 16 + n;
    size_t base = ((size_t)q * NCHUNK + ch) * 4096 + (size_t)kt * 1024 + lane * 8 + j;
    _Float16 hh = (_Float16)v;
    packB[base]       = hh;                          // hi
    packB[base + 512] = (_Float16)(v - (float)hh);   // lo
  }
  cvec64[q * KC + code] = s;
  cvec32[q * KC + code] = (float)s;
}

// ALL 4 STAGES FUSED. Residual state lives ONLY in registers as the fp16
// hi/lo split (ah+al ~1e-6 abs accurate; R2 anchor: top-2 gaps >~1e-3 so no
// argmin flips). Update: r_new = (ah+al) - E[idx], re-split in registers.
// ALL ah/al accesses are statically indexed (rule #20 — R18's runtime-rt
// rescue read spilled the arrays to scratch: 3.9 GB FETCH).
__global__ __launch_bounds__(NTH, 4) void k_fused(
    const float* __restrict__ x, float* xq,
    const float* __restrict__ cb,
    const double* __restrict__ cvec64, const float* __restrict__ cvec32,
    const _Float16* __restrict__ packB,
    float* oidx, float* __restrict__ lpart)
{
  __shared__ _Float16 Bl[3 * 4096];   // ring-3 of 8 KB chunks = 24 KB
  __shared__ float    cvecL[KC];      // 4 KB
  __shared__ int      idxsW[BM];      // working idx (+flag bit16)
  __shared__ float    rowbuf[DIM];    // rescue row broadcast
  __shared__ double   redd[NWAVE];
  __shared__ int      redi[NWAVE];
  __shared__ float    redf[NWAVE];
  __shared__ int      flags[NWAVE];

  const int tid = threadIdx.x;
  const int lane = tid & 63, wv = tid >> 6;
  const int tx = lane & 15;
  const size_t rowbase = (size_t)blockIdx.x * BM;

  // ---- prologue: A-fragments of x (2 rowtiles x 4 ktiles, fp16 hi/lo)
  h8 ah[2][4], al[2][4];
  #pragma unroll
  for (int rt = 0; rt < 2; rt++) {
    const float* rowp = x + (rowbase + wv * 32 + rt * 16 + (lane & 15)) * (size_t)DIM
                        + ((lane >> 4) * 8);
    #pragma unroll
    for (int kt = 0; kt < 4; kt++) {
      float4 f0 = *(const float4*)(rowp + kt * 32);
      float4 f1 = *(const float4*)(rowp + kt * 32 + 4);
      float vv[8] = {f0.x, f0.y, f0.z, f0.w, f1.x, f1.y, f1.z, f1.w};
      #pragma unroll
      for (int j = 0; j < 8; j++) {
        _Float16 hh = (_Float16)vv[j];
        ah[rt][kt][j] = hh;
        al[rt][kt][j] = (_Float16)(vv[j] - (float)hh);
      }
    }
  }

  float lsum = 0.f;
  const fx4 zero4 = {0.f, 0.f, 0.f, 0.f};

  #pragma unroll 1
  for (int st = 0; st < QST; st++) {
    const _Float16* PBq  = packB + (size_t)st * 262144;
    const float*    cq32 = cvec32 + st * KC;
    const double*   cq64 = cvec64 + st * KC;
    const float*    Eq   = cb + (size_t)st * KC * DIM;

    __syncthreads();   // prior stage quiesced (LDS reads done, vmcnt drained)
    for (int i = tid; i < KC; i += NTH) cvecL[i] = cq32[i];
    __syncthreads();   // cvecL visible; drains all preceding VMEM (vmcnt->0)

    // ---- main loop: VERBATIM round-13 structure (ring-3, counted vmcnt(2))
    auto stageB = [&](int ch, int buf) {
      const _Float16* src = PBq + (size_t)ch * 4096 + wv * 1024 + lane * 8;
      _Float16* dst = Bl + (size_t)buf * 4096 + wv * 1024;   // wave-uniform base
      #pragma unroll
      for (int i = 0; i < 2; i++)
        __builtin_amdgcn_global_load_lds((glb_void*)(src + i * 512),
                                         (lds_void*)(dst + i * 512), 16, 0, 0);
    };

    float b1[8], b2[8];
    int   i1[8];
    #pragma unroll
    for (int i = 0; i < 8; i++) { b1[i] = 3.4e38f; b2[i] = 3.4e38f; i1[i] = 0; }

    fx4 accPrev[2];
    accPrev[0] = zero4; accPrev[1] = zero4;

    stageB(0, 0); stageB(1, 1);

    int buf = 0, bufStage = 2;   // buf = ch%3, bufStage = (ch+2)%3
    #pragma unroll 1
    for (int ch = 0; ch < NCHUNK; ch++) {
      if (ch < NCHUNK - 1) asm volatile("s_waitcnt vmcnt(2)" ::: "memory");
      else                 asm volatile("s_waitcnt vmcnt(0)" ::: "memory");
      __builtin_amdgcn_s_barrier();     // all waves' ch-loads visible; buf (ch-1)%3 retired
      asm volatile("" ::: "memory");    // pin the stage below the barrier
      if (ch + 2 < NCHUNK) stageB(ch + 2, bufStage);

      // deferred score of chunk ch-1 (register-only)
      if (ch > 0) {
        int code = (ch - 1) * 16 + tx;
        float cvv = cvecL[code];
        #pragma unroll
        for (int rt = 0; rt < 2; rt++) {
          #pragma unroll
          for (int j = 0; j < 4; j++) {
            float sc = fmaf(-2.f, accPrev[rt][j], cvv);
            int r = rt * 4 + j;
            if (sc < b1[r]) { b2[r] = b1[r]; b1[r] = sc; i1[r] = code; }
            else            { b2[r] = fminf(b2[r], sc); }
          }
        }
      }

      const _Float16* Bb = Bl + (size_t)buf * 4096;
      fx4 acc[2];
      acc[0] = zero4; acc[1] = zero4;

      __builtin_amdgcn_s_setprio(1);
      #pragma unroll
      for (int kt = 0; kt < 4; kt++) {
        const _Float16* p = Bb + (size_t)kt * 1024 + lane * 8;
        h8 bh = *(const h8*)p;
        h8 bl = *(const h8*)(p + 512);
        #pragma unroll
        for (int rt = 0; rt < 2; rt++) {
          acc[rt] = MFMA16(ah[rt][kt], bh, acc[rt]);
          acc[rt] = MFMA16(al[rt][kt], bh, acc[rt]);
          acc[rt] = MFMA16(ah[rt][kt], bl, acc[rt]);
        }
      }
      __builtin_amdgcn_s_setprio(0);

      accPrev[0] = acc[0];
      accPrev[1] = acc[1];

      buf = (buf == 2) ? 0 : buf + 1;
      bufStage = (bufStage == 2) ? 0 : bufStage + 1;
    }

    // tail score
    {
      int code = (NCHUNK - 1) * 16 + tx;
      float cvv = cvecL[code];
      #pragma unroll
      for (int rt = 0; rt < 2; rt++) {
        #pragma unroll
        for (int j = 0; j < 4; j++) {
          float sc = fmaf(-2.f, accPrev[rt][j], cvv);
          int r = rt * 4 + j;
          if (sc < b1[r]) { b2[r] = b1[r]; b1[r] = sc; i1[r] = code; }
          else            { b2[r] = fminf(b2[r], sc); }
        }
      }
    }

    // ---- cross-lane top-2 reduce over the 16 lanes sharing each row
    #pragma unroll
    for (int m = 1; m < 16; m <<= 1) {
      #pragma unroll
      for (int r = 0; r < 8; r++) {
        float ob1 = __shfl_xor(b1[r], m, 64);
        int   oi1 = __shfl_xor(i1[r], m, 64);
        float ob2 = __shfl_xor(b2[r], m, 64);
        bool take = (ob1 < b1[r]) || (ob1 == b1[r] && oi1 < i1[r]);
        float loser = take ? b1[r] : ob1;
        if (take) { b1[r] = ob1; i1[r] = oi1; }
        b2[r] = fminf(fminf(b2[r], ob2), loser);
      }
    }

    if (tx == 0) {
      int g = lane >> 4;
      #pragma unroll
      for (int rt = 0; rt < 2; rt++)
        #pragma unroll
        for (int j = 0; j < 4; j++) {
          int r = rt * 4 + j;
          int fl = (b2[r] - b1[r] <= EPS) ? FLAGB : 0;
          idxsW[wv * 32 + rt * 16 + g * 4 + j] = i1[r] | fl;
        }
    }
    __syncthreads();

    // ---- exact fp64 rescue (rare): row vector = registers' (ah+al), written
    //      to LDS by owner lanes with STATIC rt indexing (rule #20)
    {
      bool pred = (tid < BM) && (idxsW[tid] & FLAGB);
      unsigned long long bal = __ballot(pred);
      if (lane == 0) flags[wv] = (bal != 0ull) ? 1 : 0;
    }
    __syncthreads();
    int anyflag = flags[0] | flags[1] | flags[2] | flags[3];
    if (anyflag) {
      for (int row = 0; row < BM; row++) {
        if (!(idxsW[row] & FLAGB)) continue;       // uniform branch
        #pragma unroll
        for (int rt = 0; rt < 2; rt++) {           // rt is COMPILE-TIME here
          if ((row >> 5) == wv && ((row >> 4) & 1) == rt && (lane & 15) == (row & 15)) {
            int d0b = (lane >> 4) * 8;
            #pragma unroll
            for (int kt = 0; kt < 4; kt++)
              #pragma unroll
              for (int j = 0; j < 8; j++)
                rowbuf[d0b + kt * 32 + j] = (float)ah[rt][kt][j] + (float)al[rt][kt][j];
          }
        }
        __syncthreads();
        double dot[4] = {0.0, 0.0, 0.0, 0.0};
        for (int d = 0; d < DIM; d++) {
          double a = (double)rowbuf[d];            // LDS broadcast
          #pragma unroll
          for (int c = 0; c < 4; c++)
            dot[c] = fma(a, (double)Eq[(size_t)(tid + c * NTH) * DIM + d], dot[c]);
        }
        double bs = 1e300; int bk = 0;
        #pragma unroll
        for (int c = 0; c < 4; c++) {
          int k = tid + c * NTH;
          double s = fma(-2.0, dot[c], cq64[k]);
          if (s < bs || (s == bs && k < bk)) { bs = s; bk = k; }
        }
        #pragma unroll
        for (int m = 1; m < 64; m <<= 1) {
          double ob = __shfl_xor(bs, m, 64);
          int    ok = __shfl_xor(bk, m, 64);
          if (ob < bs || (ob == bs && ok < bk)) { bs = ob; bk = ok; }
        }
        if (lane == 0) { redd[wv] = bs; redi[wv] = bk; }
        __syncthreads();
        if (tid == 0) {
          double fb = redd[0]; int fk = redi[0];
          #pragma unroll
          for (int w = 1; w < NWAVE; w++) {
            if (redd[w] < fb || (redd[w] == fb && redi[w] < fk)) { fb = redd[w]; fk = redi[w]; }
          }
          idxsW[row] = fk;                         // flag cleared
        }
        __syncthreads();
      }
    }

    // ---- finalize indices for this stage
    if (tid < BM) oidx[(rowbase + tid) * 4 + st] = (float)(idxsW[tid] & 1023);
    __syncthreads();

    // ---- register-local update: r_new = (ah+al) - E[idx]; loss += r_new^2;
    //      st<3 -> re-split into ah/al; st==3 -> x_q = x - r_new
    #pragma unroll
    for (int rt = 0; rt < 2; rt++) {
      int row = wv * 32 + rt * 16 + (lane & 15);
      int kidx = idxsW[row] & 1023;
      int d0b = (lane >> 4) * 8;
      #pragma unroll
      for (int kt = 0; kt < 4; kt++) {
        int d0 = d0b + kt * 32;
        const float* ep = Eq + (size_t)kidx * DIM + d0;
        float4 e0 = *(const float4*)(ep);
        float4 e1 = *(const float4*)(ep + 4);
        float e8[8] = {e0.x, e0.y, e0.z, e0.w, e1.x, e1.y, e1.z, e1.w};
        float r8[8];
        #pragma unroll
        for (int j = 0; j < 8; j++) {
          r8[j] = ((float)ah[rt][kt][j] + (float)al[rt][kt][j]) - e8[j];
          lsum = fmaf(r8[j], r8[j], lsum);
        }
        if (st < QST - 1) {
          #pragma unroll
          for (int j = 0; j < 8; j++) {
            _Float16 hh = (_Float16)r8[j];
            ah[rt][kt][j] = hh;
            al[rt][kt][j] = (_Float16)(r8[j] - (float)hh);
          }
        } else {
          const float* xp = x + (rowbase + row) * (size_t)DIM + d0;
          float4 xf0 = *(const float4*)(xp);
          float4 xf1 = *(const float4*)(xp + 4);
          float* op = xq + (rowbase + row) * (size_t)DIM + d0;
          *(float4*)(op)     = make_float4(xf0.x - r8[0], xf0.y - r8[1],
                                           xf0.z - r8[2], xf0.w - r8[3]);
          *(float4*)(op + 4) = make_float4(xf1.x - r8[4], xf1.y - r8[5],
                                           xf1.z - r8[6], xf1.w - r8[7]);
        }
      }
    }
  }

  // ---- block loss reduce -> lpart[block]
  #pragma unroll
  for (int m = 1; m < 64; m <<= 1) lsum += __shfl_xor(lsum, m, 64);
  if (lane == 0) redf[wv] = lsum;
  __syncthreads();
  if (tid == 0) lpart[blockIdx.x] = redf[0] + redf[1] + redf[2] + redf[3];
}

__global__ void k_loss(const float* __restrict__ part, float* __restrict__ o) {
  __shared__ float red[4];
  int tid = threadIdx.x;
  float s = 0.f;
  for (int i = tid; i < N_ROWS / BM; i += PNTH) s += part[i];
  #pragma unroll
  for (int m = 1; m < 64; m <<= 1) s += __shfl_xor(s, m, 64);
  if ((tid & 63) == 0) red[tid >> 6] = s;
  __syncthreads();
  if (tid == 0)
    o[0] = (red[0] + red[1] + red[2] + red[3]) *
           (1.25f / ((float)QST * (float)N_ROWS * (float)DIM));
}

extern "C" void kernel_launch(void* const* d_in, const int* in_sizes, int n_in,
                              void* d_out, int out_size, void* d_ws, size_t ws_size,
                              hipStream_t stream) {
  const float* x  = (const float*)d_in[0];
  const float* cb = (const float*)d_in[1];
  float* out = (float*)d_out;
  float* ws  = (float*)d_ws;

  double*   cvec64 = (double*)ws;                           // Q*K fp64 ||E||^2
  float*    cvec32 = (float*)(cvec64 + (size_t)QST * KC);
  float*    part   = cvec32 + (size_t)QST * KC;             // 1024 loss partials
  _Float16* packB  = (_Float16*)(part + (size_t)(N_ROWS / BM)); // 2 MB frags

  float* out_loss = out + (size_t)N_ROWS * DIM;
  float* out_idx  = out_loss + 1;

  k_prep<<<(QST * KC + PNTH - 1) / PNTH, PNTH, 0, stream>>>(cb, cvec64, cvec32, packB);

  k_fused<<<N_ROWS / BM, NTH, 0, stream>>>(x, out, cb, cvec64, cvec32, packB,
                                           out_idx, part);

  k_loss<<<1, PNTH, 0, stream>>>(part, out_loss);
}

// Round 20
// 708.799 us; speedup vs baseline: 2.3121x; 1.0180x over previous
//
#include <hip/hip_runtime.h>

#define N_ROWS 131072
#define DIM    128
#define QST    4
#define KC     1024
#define BM     128     // rows per workgroup (4 waves x 32 rows)
#define NTH    256
#define PNTH   256
#define NWAVE  4
#define NCHUNK 64      // 16 codes per chunk, 8 KB fragments
#define EPS    6e-3f   // certified fp16-split argmin margin
#define FLAGB  (1 << 16)

typedef _Float16 h8  __attribute__((ext_vector_type(8)));
typedef float    fx4 __attribute__((ext_vector_type(4)));

typedef __attribute__((address_space(3))) void lds_void;
typedef const __attribute__((address_space(1))) void glb_void;

#define MFMA16(a, b, c) __builtin_amdgcn_mfma_f32_16x16x32_f16((a), (b), (c), 0, 0, 0)

// packB halfs layout: [q][ch(64)][kt(4)][hl(2)][lane(64)][j(8)]
__global__ void k_prep(const float* __restrict__ cb,
                       double* __restrict__ cvec64, float* __restrict__ cvec32,
                       _Float16* __restrict__ packB) {
  int gid = blockIdx.x * blockDim.x + threadIdx.x;
  if (gid >= QST * KC) return;
  int q = gid >> 10, code = gid & (KC - 1);
  int ch = code >> 4, n = code & 15;
  const float* e = cb + ((size_t)q * KC + code) * DIM;
  double s = 0.0;
  for (int d = 0; d < DIM; d++) {
    float v = e[d];
    s = fma((double)v, (double)v, s);
    int kt = d >> 5, g = (d >> 3) & 3, j = d & 7;
    int lane = g * 16 + n;
    size_t base = ((size_t)q * NCHUNK + ch) * 4096 + (size_t)kt * 1024 + lane * 8 + j;
    _Float16 hh = (_Float16)v;
    packB[base]       = hh;                          // hi
    packB[base + 512] = (_Float16)(v - (float)hh);   // lo
  }
  cvec64[q * KC + code] = s;
  cvec32[q * KC + code] = (float)s;
}

// ALL 4 STAGES FUSED. Residual state lives ONLY in registers as the fp16
// hi/lo split (ah+al ~1e-6 abs accurate; R2 anchor: top-2 gaps >~1e-3 so no
// argmin flips). Update: r_new = (ah+al) - E[idx], re-split in registers.
// ALL ah/al accesses are statically indexed (rule #20 — R18's runtime-rt
// rescue read spilled the arrays to scratch: 3.9 GB FETCH).
__global__ __launch_bounds__(NTH, 4) void k_fused(
    const float* __restrict__ x, float* xq,
    const float* __restrict__ cb,
    const double* __restrict__ cvec64, const float* __restrict__ cvec32,
    const _Float16* __restrict__ packB,
    float* oidx, float* __restrict__ lpart)
{
  __shared__ _Float16 Bl[3 * 4096];   // ring-3 of 8 KB chunks = 24 KB
  __shared__ float    cvecL[KC];      // 4 KB
  __shared__ int      idxsW[BM];      // working idx (+flag bit16)
  __shared__ float    rowbuf[DIM];    // rescue row broadcast
  __shared__ double   redd[NWAVE];
  __shared__ int      redi[NWAVE];
  __shared__ float    redf[NWAVE];
  __shared__ int      flags[NWAVE];

  const int tid = threadIdx.x;
  const int lane = tid & 63, wv = tid >> 6;
  const int tx = lane & 15;
  const size_t rowbase = (size_t)blockIdx.x * BM;

  // ---- prologue: A-fragments of x (2 rowtiles x 4 ktiles, fp16 hi/lo)
  h8 ah[2][4], al[2][4];
  #pragma unroll
  for (int rt = 0; rt < 2; rt++) {
    const float* rowp = x + (rowbase + wv * 32 + rt * 16 + (lane & 15)) * (size_t)DIM
                        + ((lane >> 4) * 8);
    #pragma unroll
    for (int kt = 0; kt < 4; kt++) {
      float4 f0 = *(const float4*)(rowp + kt * 32);
      float4 f1 = *(const float4*)(rowp + kt * 32 + 4);
      float vv[8] = {f0.x, f0.y, f0.z, f0.w, f1.x, f1.y, f1.z, f1.w};
      #pragma unroll
      for (int j = 0; j < 8; j++) {
        _Float16 hh = (_Float16)vv[j];
        ah[rt][kt][j] = hh;
        al[rt][kt][j] = (_Float16)(vv[j] - (float)hh);
      }
    }
  }

  float lsum = 0.f;
  const fx4 zero4 = {0.f, 0.f, 0.f, 0.f};

  #pragma unroll 1
  for (int st = 0; st < QST; st++) {
    const _Float16* PBq  = packB + (size_t)st * 262144;
    const float*    cq32 = cvec32 + st * KC;
    const double*   cq64 = cvec64 + st * KC;
    const float*    Eq   = cb + (size_t)st * KC * DIM;

    __syncthreads();   // prior stage quiesced (LDS reads done, vmcnt drained)
    for (int i = tid; i < KC; i += NTH) cvecL[i] = cq32[i];
    __syncthreads();   // cvecL visible; drains all preceding VMEM (vmcnt->0)

    // ---- main loop: VERBATIM round-13 structure (ring-3, counted vmcnt(2))
    auto stageB = [&](int ch, int buf) {
      const _Float16* src = PBq + (size_t)ch * 4096 + wv * 1024 + lane * 8;
      _Float16* dst = Bl + (size_t)buf * 4096 + wv * 1024;   // wave-uniform base
      #pragma unroll
      for (int i = 0; i < 2; i++)
        __builtin_amdgcn_global_load_lds((glb_void*)(src + i * 512),
                                         (lds_void*)(dst + i * 512), 16, 0, 0);
    };

    float b1[8], b2[8];
    int   i1[8];
    #pragma unroll
    for (int i = 0; i < 8; i++) { b1[i] = 3.4e38f; b2[i] = 3.4e38f; i1[i] = 0; }

    fx4 accPrev[2];
    accPrev[0] = zero4; accPrev[1] = zero4;

    stageB(0, 0); stageB(1, 1);

    int buf = 0, bufStage = 2;   // buf = ch%3, bufStage = (ch+2)%3
    #pragma unroll 1
    for (int ch = 0; ch < NCHUNK; ch++) {
      if (ch < NCHUNK - 1) asm volatile("s_waitcnt vmcnt(2)" ::: "memory");
      else                 asm volatile("s_waitcnt vmcnt(0)" ::: "memory");
      __builtin_amdgcn_s_barrier();     // all waves' ch-loads visible; buf (ch-1)%3 retired
      asm volatile("" ::: "memory");    // pin the stage below the barrier
      if (ch + 2 < NCHUNK) stageB(ch + 2, bufStage);

      // deferred score of chunk ch-1 (register-only)
      if (ch > 0) {
        int code = (ch - 1) * 16 + tx;
        float cvv = cvecL[code];
        #pragma unroll
        for (int rt = 0; rt < 2; rt++) {
          #pragma unroll
          for (int j = 0; j < 4; j++) {
            float sc = fmaf(-2.f, accPrev[rt][j], cvv);
            int r = rt * 4 + j;
            if (sc < b1[r]) { b2[r] = b1[r]; b1[r] = sc; i1[r] = code; }
            else            { b2[r] = fminf(b2[r], sc); }
          }
        }
      }

      const _Float16* Bb = Bl + (size_t)buf * 4096;
      fx4 acc[2];
      acc[0] = zero4; acc[1] = zero4;

      __builtin_amdgcn_s_setprio(1);
      #pragma unroll
      for (int kt = 0; kt < 4; kt++) {
        const _Float16* p = Bb + (size_t)kt * 1024 + lane * 8;
        h8 bh = *(const h8*)p;
        h8 bl = *(const h8*)(p + 512);
        #pragma unroll
        for (int rt = 0; rt < 2; rt++) {
          acc[rt] = MFMA16(ah[rt][kt], bh, acc[rt]);
          acc[rt] = MFMA16(al[rt][kt], bh, acc[rt]);
          acc[rt] = MFMA16(ah[rt][kt], bl, acc[rt]);
        }
      }
      __builtin_amdgcn_s_setprio(0);

      accPrev[0] = acc[0];
      accPrev[1] = acc[1];

      buf = (buf == 2) ? 0 : buf + 1;
      bufStage = (bufStage == 2) ? 0 : bufStage + 1;
    }

    // tail score
    {
      int code = (NCHUNK - 1) * 16 + tx;
      float cvv = cvecL[code];
      #pragma unroll
      for (int rt = 0; rt < 2; rt++) {
        #pragma unroll
        for (int j = 0; j < 4; j++) {
          float sc = fmaf(-2.f, accPrev[rt][j], cvv);
          int r = rt * 4 + j;
          if (sc < b1[r]) { b2[r] = b1[r]; b1[r] = sc; i1[r] = code; }
          else            { b2[r] = fminf(b2[r], sc); }
        }
      }
    }

    // ---- cross-lane top-2 reduce over the 16 lanes sharing each row
    #pragma unroll
    for (int m = 1; m < 16; m <<= 1) {
      #pragma unroll
      for (int r = 0; r < 8; r++) {
        float ob1 = __shfl_xor(b1[r], m, 64);
        int   oi1 = __shfl_xor(i1[r], m, 64);
        float ob2 = __shfl_xor(b2[r], m, 64);
        bool take = (ob1 < b1[r]) || (ob1 == b1[r] && oi1 < i1[r]);
        float loser = take ? b1[r] : ob1;
        if (take) { b1[r] = ob1; i1[r] = oi1; }
        b2[r] = fminf(fminf(b2[r], ob2), loser);
      }
    }

    if (tx == 0) {
      int g = lane >> 4;
      #pragma unroll
      for (int rt = 0; rt < 2; rt++)
        #pragma unroll
        for (int j = 0; j < 4; j++) {
          int r = rt * 4 + j;
          int fl = (b2[r] - b1[r] <= EPS) ? FLAGB : 0;
          idxsW[wv * 32 + rt * 16 + g * 4 + j] = i1[r] | fl;
        }
    }
    __syncthreads();

    // ---- exact fp64 rescue (rare): row vector = registers' (ah+al), written
    //      to LDS by owner lanes with STATIC rt indexing (rule #20)
    {
      bool pred = (tid < BM) && (idxsW[tid] & FLAGB);
      unsigned long long bal = __ballot(pred);
      if (lane == 0) flags[wv] = (bal != 0ull) ? 1 : 0;
    }
    __syncthreads();
    int anyflag = flags[0] | flags[1] | flags[2] | flags[3];
    if (anyflag) {
      for (int row = 0; row < BM; row++) {
        if (!(idxsW[row] & FLAGB)) continue;       // uniform branch
        #pragma unroll
        for (int rt = 0; rt < 2; rt++) {           // rt is COMPILE-TIME here
          if ((row >> 5) == wv && ((row >> 4) & 1) == rt && (lane & 15) == (row & 15)) {
            int d0b = (lane >> 4) * 8;
            #pragma unroll
            for (int kt = 0; kt < 4; kt++)
              #pragma unroll
              for (int j = 0; j < 8; j++)
                rowbuf[d0b + kt * 32 + j] = (float)ah[rt][kt][j] + (float)al[rt][kt][j];
          }
        }
        __syncthreads();
        double dot[4] = {0.0, 0.0, 0.0, 0.0};
        for (int d = 0; d < DIM; d++) {
          double a = (double)rowbuf[d];            // LDS broadcast
          #pragma unroll
          for (int c = 0; c < 4; c++)
            dot[c] = fma(a, (double)Eq[(size_t)(tid + c * NTH) * DIM + d], dot[c]);
        }
        double bs = 1e300; int bk = 0;
        #pragma unroll
        for (int c = 0; c < 4; c++) {
          int k = tid + c * NTH;
          double s = fma(-2.0, dot[c], cq64[k]);
          if (s < bs || (s == bs && k < bk)) { bs = s; bk = k; }
        }
        #pragma unroll
        for (int m = 1; m < 64; m <<= 1) {
          double ob = __shfl_xor(bs, m, 64);
          int    ok = __shfl_xor(bk, m, 64);
          if (ob < bs || (ob == bs && ok < bk)) { bs = ob; bk = ok; }
        }
        if (lane == 0) { redd[wv] = bs; redi[wv] = bk; }
        __syncthreads();
        if (tid == 0) {
          double fb = redd[0]; int fk = redi[0];
          #pragma unroll
          for (int w = 1; w < NWAVE; w++) {
            if (redd[w] < fb || (redd[w] == fb && redi[w] < fk)) { fb = redd[w]; fk = redi[w]; }
          }
          idxsW[row] = fk;                         // flag cleared
        }
        __syncthreads();
      }
    }

    // ---- finalize indices for this stage
    if (tid < BM) oidx[(rowbase + tid) * 4 + st] = (float)(idxsW[tid] & 1023);
    __syncthreads();

    // ---- register-local update: r_new = (ah+al) - E[idx]; loss += r_new^2;
    //      st<3 -> re-split into ah/al; st==3 -> x_q = x - r_new
    #pragma unroll
    for (int rt = 0; rt < 2; rt++) {
      int row = wv * 32 + rt * 16 + (lane & 15);
      int kidx = idxsW[row] & 1023;
      int d0b = (lane >> 4) * 8;
      #pragma unroll
      for (int kt = 0; kt < 4; kt++) {
        int d0 = d0b + kt * 32;
        const float* ep = Eq + (size_t)kidx * DIM + d0;
        float4 e0 = *(const float4*)(ep);
        float4 e1 = *(const float4*)(ep + 4);
        float e8[8] = {e0.x, e0.y, e0.z, e0.w, e1.x, e1.y, e1.z, e1.w};
        float r8[8];
        #pragma unroll
        for (int j = 0; j < 8; j++) {
          r8[j] = ((float)ah[rt][kt][j] + (float)al[rt][kt][j]) - e8[j];
          lsum = fmaf(r8[j], r8[j], lsum);
        }
        if (st < QST - 1) {
          #pragma unroll
          for (int j = 0; j < 8; j++) {
            _Float16 hh = (_Float16)r8[j];
            ah[rt][kt][j] = hh;
            al[rt][kt][j] = (_Float16)(r8[j] - (float)hh);
          }
        } else {
          const float* xp = x + (rowbase + row) * (size_t)DIM + d0;
          float4 xf0 = *(const float4*)(xp);
          float4 xf1 = *(const float4*)(xp + 4);
          float* op = xq + (rowbase + row) * (size_t)DIM + d0;
          *(float4*)(op)     = make_float4(xf0.x - r8[0], xf0.y - r8[1],
                                           xf0.z - r8[2], xf0.w - r8[3]);
          *(float4*)(op + 4) = make_float4(xf1.x - r8[4], xf1.y - r8[5],
                                           xf1.z - r8[6], xf1.w - r8[7]);
        }
      }
    }
  }

  // ---- block loss reduce -> lpart[block]
  #pragma unroll
  for (int m = 1; m < 64; m <<= 1) lsum += __shfl_xor(lsum, m, 64);
  if (lane == 0) redf[wv] = lsum;
  __syncthreads();
  if (tid == 0) lpart[blockIdx.x] = redf[0] + redf[1] + redf[2] + redf[3];
}

__global__ void k_loss(const float* __restrict__ part, float* __restrict__ o) {
  __shared__ float red[4];
  int tid = threadIdx.x;
  float s = 0.f;
  for (int i = tid; i < N_ROWS / BM; i += PNTH) s += part[i];
  #pragma unroll
  for (int m = 1; m < 64; m <<= 1) s += __shfl_xor(s, m, 64);
  if ((tid & 63) == 0) red[tid >> 6] = s;
  __syncthreads();
  if (tid == 0)
    o[0] = (red[0] + red[1] + red[2] + red[3]) *
           (1.25f / ((float)QST * (float)N_ROWS * (float)DIM));
}

extern "C" void kernel_launch(void* const* d_in, const int* in_sizes, int n_in,
                              void* d_out, int out_size, void* d_ws, size_t ws_size,
                              hipStream_t stream) {
  const float* x  = (const float*)d_in[0];
  const float* cb = (const float*)d_in[1];
  float* out = (float*)d_out;
  float* ws  = (float*)d_ws;

  double*   cvec64 = (double*)ws;                           // Q*K fp64 ||E||^2
  float*    cvec32 = (float*)(cvec64 + (size_t)QST * KC);
  float*    part   = cvec32 + (size_t)QST * KC;             // 1024 loss partials
  _Float16* packB  = (_Float16*)(part + (size_t)(N_ROWS / BM)); // 2 MB frags

  float* out_loss = out + (size_t)N_ROWS * DIM;
  float* out_idx  = out_loss + 1;

  k_prep<<<(QST * KC + PNTH - 1) / PNTH, PNTH, 0, stream>>>(cb, cvec64, cvec32, packB);

  k_fused<<<N_ROWS / BM, NTH, 0, stream>>>(x, out, cb, cvec64, cvec32, packB,
                                           out_idx, part);

  k_loss<<<1, PNTH, 0, stream>>>(part, out_loss);
}

// Round 21
// 563.158 us; speedup vs baseline: 2.9101x; 1.2586x over previous
//
#include <hip/hip_runtime.h>

#define N_ROWS 131072
#define DIM    128
#define QST    4
#define KC     1024
#define BM     128     // rows per workgroup (4 waves x 32 rows)
#define NTH    256
#define PNTH   256
#define NWAVE  4
#define NCHUNK 64      // 16 codes per chunk, 8 KB fragments
#define EPS    6e-3f   // certified fp16-split argmin margin
#define FLAGB  (1 << 16)

typedef _Float16 h8  __attribute__((ext_vector_type(8)));
typedef float    fx4 __attribute__((ext_vector_type(4)));

typedef __attribute__((address_space(3))) void lds_void;
typedef const __attribute__((address_space(1))) void glb_void;

#define MFMA16(a, b, c) __builtin_amdgcn_mfma_f32_16x16x32_f16((a), (b), (c), 0, 0, 0)

// packB halfs layout: [q][ch(64)][kt(4)][hl(2)][lane(64)][j(8)]
__global__ void k_prep(const float* __restrict__ cb,
                       double* __restrict__ cvec64, float* __restrict__ cvec32,
                       _Float16* __restrict__ packB) {
  int gid = blockIdx.x * blockDim.x + threadIdx.x;
  if (gid >= QST * KC) return;
  int q = gid >> 10, code = gid & (KC - 1);
  int ch = code >> 4, n = code & 15;
  const float* e = cb + ((size_t)q * KC + code) * DIM;
  double s = 0.0;
  for (int d = 0; d < DIM; d++) {
    float v = e[d];
    s = fma((double)v, (double)v, s);
    int kt = d >> 5, g = (d >> 3) & 3, j = d & 7;
    int lane = g * 16 + n;
    size_t base = ((size_t)q * NCHUNK + ch) * 4096 + (size_t)kt * 1024 + lane * 8 + j;
    _Float16 hh = (_Float16)v;
    packB[base]       = hh;                          // hi
    packB[base + 512] = (_Float16)(v - (float)hh);   // lo
  }
  cvec64[q * KC + code] = s;
  cvec32[q * KC + code] = (float)s;
}

// ALL 4 STAGES FUSED. Residual state lives ONLY in registers as the fp16
// hi/lo split; update r_new = (ah+al) - E[idx], re-split in registers.
// Spill mitigation vs R20: (1) launch_bounds(,2) lifts the 128-VGPR cap;
// (2) rescue never reads ah/al (row rebuilt from x and the LDS idx history),
// so the register state is only touched in straight-line code.
__global__ __launch_bounds__(NTH, 2) void k_fused(
    const float* __restrict__ x, float* xq,
    const float* __restrict__ cb,
    const double* __restrict__ cvec64, const float* __restrict__ cvec32,
    const _Float16* __restrict__ packB,
    float* oidx, float* __restrict__ lpart)
{
  __shared__ _Float16 Bl[3 * 4096];   // ring-3 of 8 KB chunks = 24 KB
  __shared__ float    cvecL[KC];      // 4 KB
  __shared__ int      idxsW[BM];      // working idx (+flag bit16)
  __shared__ int      idxH[QST][BM];  // per-stage index history (rescue source)
  __shared__ float    rowbuf[DIM];    // rescue row broadcast
  __shared__ double   redd[NWAVE];
  __shared__ int      redi[NWAVE];
  __shared__ float    redf[NWAVE];
  __shared__ int      flags[NWAVE];

  const int tid = threadIdx.x;
  const int lane = tid & 63, wv = tid >> 6;
  const int tx = lane & 15;
  const size_t rowbase = (size_t)blockIdx.x * BM;

  // ---- prologue: A-fragments of x (2 rowtiles x 4 ktiles, fp16 hi/lo)
  h8 ah[2][4], al[2][4];
  #pragma unroll
  for (int rt = 0; rt < 2; rt++) {
    const float* rowp = x + (rowbase + wv * 32 + rt * 16 + (lane & 15)) * (size_t)DIM
                        + ((lane >> 4) * 8);
    #pragma unroll
    for (int kt = 0; kt < 4; kt++) {
      float4 f0 = *(const float4*)(rowp + kt * 32);
      float4 f1 = *(const float4*)(rowp + kt * 32 + 4);
      float vv[8] = {f0.x, f0.y, f0.z, f0.w, f1.x, f1.y, f1.z, f1.w};
      #pragma unroll
      for (int j = 0; j < 8; j++) {
        _Float16 hh = (_Float16)vv[j];
        ah[rt][kt][j] = hh;
        al[rt][kt][j] = (_Float16)(vv[j] - (float)hh);
      }
    }
  }

  float lsum = 0.f;
  const fx4 zero4 = {0.f, 0.f, 0.f, 0.f};

  #pragma unroll 1
  for (int st = 0; st < QST; st++) {
    const _Float16* PBq  = packB + (size_t)st * 262144;
    const float*    cq32 = cvec32 + st * KC;
    const double*   cq64 = cvec64 + st * KC;
    const float*    Eq   = cb + (size_t)st * KC * DIM;

    __syncthreads();   // prior stage quiesced (LDS reads done, vmcnt drained)
    for (int i = tid; i < KC; i += NTH) cvecL[i] = cq32[i];
    __syncthreads();   // cvecL visible; drains all preceding VMEM (vmcnt->0)

    // ---- main loop: VERBATIM round-13 structure (ring-3, counted vmcnt(2))
    auto stageB = [&](int ch, int buf) {
      const _Float16* src = PBq + (size_t)ch * 4096 + wv * 1024 + lane * 8;
      _Float16* dst = Bl + (size_t)buf * 4096 + wv * 1024;   // wave-uniform base
      #pragma unroll
      for (int i = 0; i < 2; i++)
        __builtin_amdgcn_global_load_lds((glb_void*)(src + i * 512),
                                         (lds_void*)(dst + i * 512), 16, 0, 0);
    };

    float b1[8], b2[8];
    int   i1[8];
    #pragma unroll
    for (int i = 0; i < 8; i++) { b1[i] = 3.4e38f; b2[i] = 3.4e38f; i1[i] = 0; }

    fx4 accPrev[2];
    accPrev[0] = zero4; accPrev[1] = zero4;

    stageB(0, 0); stageB(1, 1);

    int buf = 0, bufStage = 2;   // buf = ch%3, bufStage = (ch+2)%3
    #pragma unroll 1
    for (int ch = 0; ch < NCHUNK; ch++) {
      if (ch < NCHUNK - 1) asm volatile("s_waitcnt vmcnt(2)" ::: "memory");
      else                 asm volatile("s_waitcnt vmcnt(0)" ::: "memory");
      __builtin_amdgcn_s_barrier();     // all waves' ch-loads visible; buf (ch-1)%3 retired
      asm volatile("" ::: "memory");    // pin the stage below the barrier
      if (ch + 2 < NCHUNK) stageB(ch + 2, bufStage);

      // deferred score of chunk ch-1 (register-only)
      if (ch > 0) {
        int code = (ch - 1) * 16 + tx;
        float cvv = cvecL[code];
        #pragma unroll
        for (int rt = 0; rt < 2; rt++) {
          #pragma unroll
          for (int j = 0; j < 4; j++) {
            float sc = fmaf(-2.f, accPrev[rt][j], cvv);
            int r = rt * 4 + j;
            if (sc < b1[r]) { b2[r] = b1[r]; b1[r] = sc; i1[r] = code; }
            else            { b2[r] = fminf(b2[r], sc); }
          }
        }
      }

      const _Float16* Bb = Bl + (size_t)buf * 4096;
      fx4 acc[2];
      acc[0] = zero4; acc[1] = zero4;

      __builtin_amdgcn_s_setprio(1);
      #pragma unroll
      for (int kt = 0; kt < 4; kt++) {
        const _Float16* p = Bb + (size_t)kt * 1024 + lane * 8;
        h8 bh = *(const h8*)p;
        h8 bl = *(const h8*)(p + 512);
        #pragma unroll
        for (int rt = 0; rt < 2; rt++) {
          acc[rt] = MFMA16(ah[rt][kt], bh, acc[rt]);
          acc[rt] = MFMA16(al[rt][kt], bh, acc[rt]);
          acc[rt] = MFMA16(ah[rt][kt], bl, acc[rt]);
        }
      }
      __builtin_amdgcn_s_setprio(0);

      accPrev[0] = acc[0];
      accPrev[1] = acc[1];

      buf = (buf == 2) ? 0 : buf + 1;
      bufStage = (bufStage == 2) ? 0 : bufStage + 1;
    }

    // tail score
    {
      int code = (NCHUNK - 1) * 16 + tx;
      float cvv = cvecL[code];
      #pragma unroll
      for (int rt = 0; rt < 2; rt++) {
        #pragma unroll
        for (int j = 0; j < 4; j++) {
          float sc = fmaf(-2.f, accPrev[rt][j], cvv);
          int r = rt * 4 + j;
          if (sc < b1[r]) { b2[r] = b1[r]; b1[r] = sc; i1[r] = code; }
          else            { b2[r] = fminf(b2[r], sc); }
        }
      }
    }

    // ---- cross-lane top-2 reduce over the 16 lanes sharing each row
    #pragma unroll
    for (int m = 1; m < 16; m <<= 1) {
      #pragma unroll
      for (int r = 0; r < 8; r++) {
        float ob1 = __shfl_xor(b1[r], m, 64);
        int   oi1 = __shfl_xor(i1[r], m, 64);
        float ob2 = __shfl_xor(b2[r], m, 64);
        bool take = (ob1 < b1[r]) || (ob1 == b1[r] && oi1 < i1[r]);
        float loser = take ? b1[r] : ob1;
        if (take) { b1[r] = ob1; i1[r] = oi1; }
        b2[r] = fminf(fminf(b2[r], ob2), loser);
      }
    }

    if (tx == 0) {
      int g = lane >> 4;
      #pragma unroll
      for (int rt = 0; rt < 2; rt++)
        #pragma unroll
        for (int j = 0; j < 4; j++) {
          int r = rt * 4 + j;
          int fl = (b2[r] - b1[r] <= EPS) ? FLAGB : 0;
          idxsW[wv * 32 + rt * 16 + g * 4 + j] = i1[r] | fl;
        }
    }
    __syncthreads();

    // ---- exact fp64 rescue (rare): row rebuilt as x - sum(E[idxH]) in fp32
    //      (the reference's own chain); NEVER touches ah/al registers.
    {
      bool pred = (tid < BM) && (idxsW[tid] & FLAGB);
      unsigned long long bal = __ballot(pred);
      if (lane == 0) flags[wv] = (bal != 0ull) ? 1 : 0;
    }
    __syncthreads();
    int anyflag = flags[0] | flags[1] | flags[2] | flags[3];
    if (anyflag) {
      for (int row = 0; row < BM; row++) {
        if (!(idxsW[row] & FLAGB)) continue;       // uniform branch
        if (tid < 16) {
          int d0 = tid * 8;
          const float* xp = x + (rowbase + row) * (size_t)DIM + d0;
          float r8[8];
          #pragma unroll
          for (int j = 0; j < 8; j++) r8[j] = xp[j];
          for (int s = 0; s < st; s++) {
            const float* ep = cb + ((size_t)s * KC + idxH[s][row]) * DIM + d0;
            #pragma unroll
            for (int j = 0; j < 8; j++) r8[j] = r8[j] - ep[j];
          }
          #pragma unroll
          for (int j = 0; j < 8; j++) rowbuf[d0 + j] = r8[j];
        }
        __syncthreads();
        double dot[4] = {0.0, 0.0, 0.0, 0.0};
        for (int d = 0; d < DIM; d++) {
          double a = (double)rowbuf[d];            // LDS broadcast
          #pragma unroll
          for (int c = 0; c < 4; c++)
            dot[c] = fma(a, (double)Eq[(size_t)(tid + c * NTH) * DIM + d], dot[c]);
        }
        double bs = 1e300; int bk = 0;
        #pragma unroll
        for (int c = 0; c < 4; c++) {
          int k = tid + c * NTH;
          double s = fma(-2.0, dot[c], cq64[k]);
          if (s < bs || (s == bs && k < bk)) { bs = s; bk = k; }
        }
        #pragma unroll
        for (int m = 1; m < 64; m <<= 1) {
          double ob = __shfl_xor(bs, m, 64);
          int    ok = __shfl_xor(bk, m, 64);
          if (ob < bs || (ob == bs && ok < bk)) { bs = ob; bk = ok; }
        }
        if (lane == 0) { redd[wv] = bs; redi[wv] = bk; }
        __syncthreads();
        if (tid == 0) {
          double fb = redd[0]; int fk = redi[0];
          #pragma unroll
          for (int w = 1; w < NWAVE; w++) {
            if (redd[w] < fb || (redd[w] == fb && redi[w] < fk)) { fb = redd[w]; fk = redi[w]; }
          }
          idxsW[row] = fk;                         // flag cleared
        }
        __syncthreads();
      }
    }

    // ---- finalize indices for this stage (+ history for later rescues)
    if (tid < BM) {
      int v = idxsW[tid] & 1023;
      idxH[st][tid] = v;
      oidx[(rowbase + tid) * 4 + st] = (float)v;
    }
    __syncthreads();

    // ---- register-local update: r_new = (ah+al) - E[idx]; loss += r_new^2;
    //      st<3 -> re-split into ah/al; st==3 -> x_q = x - r_new
    #pragma unroll
    for (int rt = 0; rt < 2; rt++) {
      int row = wv * 32 + rt * 16 + (lane & 15);
      int kidx = idxsW[row] & 1023;
      int d0b = (lane >> 4) * 8;
      #pragma unroll
      for (int kt = 0; kt < 4; kt++) {
        int d0 = d0b + kt * 32;
        const float* ep = Eq + (size_t)kidx * DIM + d0;
        float4 e0 = *(const float4*)(ep);
        float4 e1 = *(const float4*)(ep + 4);
        float e8[8] = {e0.x, e0.y, e0.z, e0.w, e1.x, e1.y, e1.z, e1.w};
        float r8[8];
        #pragma unroll
        for (int j = 0; j < 8; j++) {
          r8[j] = ((float)ah[rt][kt][j] + (float)al[rt][kt][j]) - e8[j];
          lsum = fmaf(r8[j], r8[j], lsum);
        }
        if (st < QST - 1) {
          #pragma unroll
          for (int j = 0; j < 8; j++) {
            _Float16 hh = (_Float16)r8[j];
            ah[rt][kt][j] = hh;
            al[rt][kt][j] = (_Float16)(r8[j] - (float)hh);
          }
        } else {
          const float* xp = x + (rowbase + row) * (size_t)DIM + d0;
          float4 xf0 = *(const float4*)(xp);
          float4 xf1 = *(const float4*)(xp + 4);
          float* op = xq + (rowbase + row) * (size_t)DIM + d0;
          *(float4*)(op)     = make_float4(xf0.x - r8[0], xf0.y - r8[1],
                                           xf0.z - r8[2], xf0.w - r8[3]);
          *(float4*)(op + 4) = make_float4(xf1.x - r8[4], xf1.y - r8[5],
                                           xf1.z - r8[6], xf1.w - r8[7]);
        }
      }
    }
  }

  // ---- block loss reduce -> lpart[block]
  #pragma unroll
  for (int m = 1; m < 64; m <<= 1) lsum += __shfl_xor(lsum, m, 64);
  if (lane == 0) redf[wv] = lsum;
  __syncthreads();
  if (tid == 0) lpart[blockIdx.x] = redf[0] + redf[1] + redf[2] + redf[3];
}

__global__ void k_loss(const float* __restrict__ part, float* __restrict__ o) {
  __shared__ float red[4];
  int tid = threadIdx.x;
  float s = 0.f;
  for (int i = tid; i < N_ROWS / BM; i += PNTH) s += part[i];
  #pragma unroll
  for (int m = 1; m < 64; m <<= 1) s += __shfl_xor(s, m, 64);
  if ((tid & 63) == 0) red[tid >> 6] = s;
  __syncthreads();
  if (tid == 0)
    o[0] = (red[0] + red[1] + red[2] + red[3]) *
           (1.25f / ((float)QST * (float)N_ROWS * (float)DIM));
}

extern "C" void kernel_launch(void* const* d_in, const int* in_sizes, int n_in,
                              void* d_out, int out_size, void* d_ws, size_t ws_size,
                              hipStream_t stream) {
  const float* x  = (const float*)d_in[0];
  const float* cb = (const float*)d_in[1];
  float* out = (float*)d_out;
  float* ws  = (float*)d_ws;

  double*   cvec64 = (double*)ws;                           // Q*K fp64 ||E||^2
  float*    cvec32 = (float*)(cvec64 + (size_t)QST * KC);
  float*    part   = cvec32 + (size_t)QST * KC;             // 1024 loss partials
  _Float16* packB  = (_Float16*)(part + (size_t)(N_ROWS / BM)); // 2 MB frags

  float* out_loss = out + (size_t)N_ROWS * DIM;
  float* out_idx  = out_loss + 1;

  k_prep<<<(QST * KC + PNTH - 1) / PNTH, PNTH, 0, stream>>>(cb, cvec64, cvec32, packB);

  k_fused<<<N_ROWS / BM, NTH, 0, stream>>>(x, out, cb, cvec64, cvec32, packB,
                                           out_idx, part);

  k_loss<<<1, PNTH, 0, stream>>>(part, out_loss);
}

// Round 22
// 551.043 us; speedup vs baseline: 2.9740x; 1.0220x over previous
//
#include <hip/hip_runtime.h>

#define N_ROWS 131072
#define DIM    128
#define QST    4
#define KC     1024
#define BM     128     // rows per workgroup (4 waves x 32 rows)
#define NTH    256
#define PNTH   256
#define NWAVE  4
#define NCHUNK 64      // 16 codes per chunk, 8 KB fragments
#define EPS    6e-3f   // certified fp16-split argmin margin
#define FLAGB  (1 << 16)

typedef _Float16 h8  __attribute__((ext_vector_type(8)));
typedef float    fx4 __attribute__((ext_vector_type(4)));

typedef __attribute__((address_space(3))) void lds_void;
typedef const __attribute__((address_space(1))) void glb_void;

#define MFMA16(a, b, c) __builtin_amdgcn_mfma_f32_16x16x32_f16((a), (b), (c), 0, 0, 0)

// packB halfs layout: [q][ch(64)][kt(4)][hl(2)][lane(64)][j(8)], lane=g*16+n.
// Vectorized: j=0..7 are contiguous at (g*128 + n*8) -> 16B h8 stores.
__global__ void k_prep(const float* __restrict__ cb,
                       double* __restrict__ cvec64, float* __restrict__ cvec32,
                       _Float16* __restrict__ packB) {
  int gid = blockIdx.x * blockDim.x + threadIdx.x;
  if (gid >= QST * KC) return;
  int q = gid >> 10, code = gid & (KC - 1);
  int ch = code >> 4, n = code & 15;
  const float* e = cb + ((size_t)q * KC + code) * DIM;
  _Float16* base = packB + ((size_t)q * NCHUNK + ch) * 4096 + n * 8;
  double s = 0.0;
  #pragma unroll
  for (int kt = 0; kt < 4; kt++) {
    #pragma unroll
    for (int g = 0; g < 4; g++) {
      float4 f0 = *(const float4*)(e + kt * 32 + g * 8);
      float4 f1 = *(const float4*)(e + kt * 32 + g * 8 + 4);
      float vv[8] = {f0.x, f0.y, f0.z, f0.w, f1.x, f1.y, f1.z, f1.w};
      h8 hi, lo;
      #pragma unroll
      for (int j = 0; j < 8; j++) {
        float v = vv[j];
        s = fma((double)v, (double)v, s);
        _Float16 hh = (_Float16)v;
        hi[j] = hh;
        lo[j] = (_Float16)(v - (float)hh);
      }
      _Float16* dst = base + kt * 1024 + g * 128;   // lane*8 = g*128 + n*8
      *(h8*)(dst)       = hi;                       // hl=0
      *(h8*)(dst + 512) = lo;                       // hl=1
    }
  }
  cvec64[q * KC + code] = s;
  cvec32[q * KC + code] = (float)s;
}

// ALL 4 STAGES FUSED (verbatim round-21). Residual state lives ONLY in
// registers as the fp16 hi/lo split; update r_new = (ah+al) - E[idx],
// re-split in registers. Rescue never reads ah/al (row rebuilt from x and
// the LDS idx history) so the register state stays in straight-line code.
__global__ __launch_bounds__(NTH, 2) void k_fused(
    const float* __restrict__ x, float* xq,
    const float* __restrict__ cb,
    const double* __restrict__ cvec64, const float* __restrict__ cvec32,
    const _Float16* __restrict__ packB,
    float* oidx, float* __restrict__ lpart)
{
  __shared__ _Float16 Bl[3 * 4096];   // ring-3 of 8 KB chunks = 24 KB
  __shared__ float    cvecL[KC];      // 4 KB
  __shared__ int      idxsW[BM];      // working idx (+flag bit16)
  __shared__ int      idxH[QST][BM];  // per-stage index history (rescue source)
  __shared__ float    rowbuf[DIM];    // rescue row broadcast
  __shared__ double   redd[NWAVE];
  __shared__ int      redi[NWAVE];
  __shared__ float    redf[NWAVE];
  __shared__ int      flags[NWAVE];

  const int tid = threadIdx.x;
  const int lane = tid & 63, wv = tid >> 6;
  const int tx = lane & 15;
  const size_t rowbase = (size_t)blockIdx.x * BM;

  // ---- prologue: A-fragments of x (2 rowtiles x 4 ktiles, fp16 hi/lo)
  h8 ah[2][4], al[2][4];
  #pragma unroll
  for (int rt = 0; rt < 2; rt++) {
    const float* rowp = x + (rowbase + wv * 32 + rt * 16 + (lane & 15)) * (size_t)DIM
                        + ((lane >> 4) * 8);
    #pragma unroll
    for (int kt = 0; kt < 4; kt++) {
      float4 f0 = *(const float4*)(rowp + kt * 32);
      float4 f1 = *(const float4*)(rowp + kt * 32 + 4);
      float vv[8] = {f0.x, f0.y, f0.z, f0.w, f1.x, f1.y, f1.z, f1.w};
      #pragma unroll
      for (int j = 0; j < 8; j++) {
        _Float16 hh = (_Float16)vv[j];
        ah[rt][kt][j] = hh;
        al[rt][kt][j] = (_Float16)(vv[j] - (float)hh);
      }
    }
  }

  float lsum = 0.f;
  const fx4 zero4 = {0.f, 0.f, 0.f, 0.f};

  #pragma unroll 1
  for (int st = 0; st < QST; st++) {
    const _Float16* PBq  = packB + (size_t)st * 262144;
    const float*    cq32 = cvec32 + st * KC;
    const double*   cq64 = cvec64 + st * KC;
    const float*    Eq   = cb + (size_t)st * KC * DIM;

    __syncthreads();   // prior stage quiesced (LDS reads done, vmcnt drained)
    for (int i = tid; i < KC; i += NTH) cvecL[i] = cq32[i];
    __syncthreads();   // cvecL visible; drains all preceding VMEM (vmcnt->0)

    // ---- main loop: VERBATIM round-13 structure (ring-3, counted vmcnt(2))
    auto stageB = [&](int ch, int buf) {
      const _Float16* src = PBq + (size_t)ch * 4096 + wv * 1024 + lane * 8;
      _Float16* dst = Bl + (size_t)buf * 4096 + wv * 1024;   // wave-uniform base
      #pragma unroll
      for (int i = 0; i < 2; i++)
        __builtin_amdgcn_global_load_lds((glb_void*)(src + i * 512),
                                         (lds_void*)(dst + i * 512), 16, 0, 0);
    };

    float b1[8], b2[8];
    int   i1[8];
    #pragma unroll
    for (int i = 0; i < 8; i++) { b1[i] = 3.4e38f; b2[i] = 3.4e38f; i1[i] = 0; }

    fx4 accPrev[2];
    accPrev[0] = zero4; accPrev[1] = zero4;

    stageB(0, 0); stageB(1, 1);

    int buf = 0, bufStage = 2;   // buf = ch%3, bufStage = (ch+2)%3
    #pragma unroll 1
    for (int ch = 0; ch < NCHUNK; ch++) {
      if (ch < NCHUNK - 1) asm volatile("s_waitcnt vmcnt(2)" ::: "memory");
      else                 asm volatile("s_waitcnt vmcnt(0)" ::: "memory");
      __builtin_amdgcn_s_barrier();     // all waves' ch-loads visible; buf (ch-1)%3 retired
      asm volatile("" ::: "memory");    // pin the stage below the barrier
      if (ch + 2 < NCHUNK) stageB(ch + 2, bufStage);

      // deferred score of chunk ch-1 (register-only)
      if (ch > 0) {
        int code = (ch - 1) * 16 + tx;
        float cvv = cvecL[code];
        #pragma unroll
        for (int rt = 0; rt < 2; rt++) {
          #pragma unroll
          for (int j = 0; j < 4; j++) {
            float sc = fmaf(-2.f, accPrev[rt][j], cvv);
            int r = rt * 4 + j;
            if (sc < b1[r]) { b2[r] = b1[r]; b1[r] = sc; i1[r] = code; }
            else            { b2[r] = fminf(b2[r], sc); }
          }
        }
      }

      const _Float16* Bb = Bl + (size_t)buf * 4096;
      fx4 acc[2];
      acc[0] = zero4; acc[1] = zero4;

      __builtin_amdgcn_s_setprio(1);
      #pragma unroll
      for (int kt = 0; kt < 4; kt++) {
        const _Float16* p = Bb + (size_t)kt * 1024 + lane * 8;
        h8 bh = *(const h8*)p;
        h8 bl = *(const h8*)(p + 512);
        #pragma unroll
        for (int rt = 0; rt < 2; rt++) {
          acc[rt] = MFMA16(ah[rt][kt], bh, acc[rt]);
          acc[rt] = MFMA16(al[rt][kt], bh, acc[rt]);
          acc[rt] = MFMA16(ah[rt][kt], bl, acc[rt]);
        }
      }
      __builtin_amdgcn_s_setprio(0);

      accPrev[0] = acc[0];
      accPrev[1] = acc[1];

      buf = (buf == 2) ? 0 : buf + 1;
      bufStage = (bufStage == 2) ? 0 : bufStage + 1;
    }

    // tail score
    {
      int code = (NCHUNK - 1) * 16 + tx;
      float cvv = cvecL[code];
      #pragma unroll
      for (int rt = 0; rt < 2; rt++) {
        #pragma unroll
        for (int j = 0; j < 4; j++) {
          float sc = fmaf(-2.f, accPrev[rt][j], cvv);
          int r = rt * 4 + j;
          if (sc < b1[r]) { b2[r] = b1[r]; b1[r] = sc; i1[r] = code; }
          else            { b2[r] = fminf(b2[r], sc); }
        }
      }
    }

    // ---- cross-lane top-2 reduce over the 16 lanes sharing each row
    #pragma unroll
    for (int m = 1; m < 16; m <<= 1) {
      #pragma unroll
      for (int r = 0; r < 8; r++) {
        float ob1 = __shfl_xor(b1[r], m, 64);
        int   oi1 = __shfl_xor(i1[r], m, 64);
        float ob2 = __shfl_xor(b2[r], m, 64);
        bool take = (ob1 < b1[r]) || (ob1 == b1[r] && oi1 < i1[r]);
        float loser = take ? b1[r] : ob1;
        if (take) { b1[r] = ob1; i1[r] = oi1; }
        b2[r] = fminf(fminf(b2[r], ob2), loser);
      }
    }

    if (tx == 0) {
      int g = lane >> 4;
      #pragma unroll
      for (int rt = 0; rt < 2; rt++)
        #pragma unroll
        for (int j = 0; j < 4; j++) {
          int r = rt * 4 + j;
          int fl = (b2[r] - b1[r] <= EPS) ? FLAGB : 0;
          idxsW[wv * 32 + rt * 16 + g * 4 + j] = i1[r] | fl;
        }
    }
    __syncthreads();

    // ---- exact fp64 rescue (rare): row rebuilt as x - sum(E[idxH]) in fp32
    //      (the reference's own chain); NEVER touches ah/al registers.
    {
      bool pred = (tid < BM) && (idxsW[tid] & FLAGB);
      unsigned long long bal = __ballot(pred);
      if (lane == 0) flags[wv] = (bal != 0ull) ? 1 : 0;
    }
    __syncthreads();
    int anyflag = flags[0] | flags[1] | flags[2] | flags[3];
    if (anyflag) {
      for (int row = 0; row < BM; row++) {
        if (!(idxsW[row] & FLAGB)) continue;       // uniform branch
        if (tid < 16) {
          int d0 = tid * 8;
          const float* xp = x + (rowbase + row) * (size_t)DIM + d0;
          float r8[8];
          #pragma unroll
          for (int j = 0; j < 8; j++) r8[j] = xp[j];
          for (int s = 0; s < st; s++) {
            const float* ep = cb + ((size_t)s * KC + idxH[s][row]) * DIM + d0;
            #pragma unroll
            for (int j = 0; j < 8; j++) r8[j] = r8[j] - ep[j];
          }
          #pragma unroll
          for (int j = 0; j < 8; j++) rowbuf[d0 + j] = r8[j];
        }
        __syncthreads();
        double dot[4] = {0.0, 0.0, 0.0, 0.0};
        for (int d = 0; d < DIM; d++) {
          double a = (double)rowbuf[d];            // LDS broadcast
          #pragma unroll
          for (int c = 0; c < 4; c++)
            dot[c] = fma(a, (double)Eq[(size_t)(tid + c * NTH) * DIM + d], dot[c]);
        }
        double bs = 1e300; int bk = 0;
        #pragma unroll
        for (int c = 0; c < 4; c++) {
          int k = tid + c * NTH;
          double s = fma(-2.0, dot[c], cq64[k]);
          if (s < bs || (s == bs && k < bk)) { bs = s; bk = k; }
        }
        #pragma unroll
        for (int m = 1; m < 64; m <<= 1) {
          double ob = __shfl_xor(bs, m, 64);
          int    ok = __shfl_xor(bk, m, 64);
          if (ob < bs || (ob == bs && ok < bk)) { bs = ob; bk = ok; }
        }
        if (lane == 0) { redd[wv] = bs; redi[wv] = bk; }
        __syncthreads();
        if (tid == 0) {
          double fb = redd[0]; int fk = redi[0];
          #pragma unroll
          for (int w = 1; w < NWAVE; w++) {
            if (redd[w] < fb || (redd[w] == fb && redi[w] < fk)) { fb = redd[w]; fk = redi[w]; }
          }
          idxsW[row] = fk;                         // flag cleared
        }
        __syncthreads();
      }
    }

    // ---- finalize indices for this stage (+ history for later rescues)
    if (tid < BM) {
      int v = idxsW[tid] & 1023;
      idxH[st][tid] = v;
      oidx[(rowbase + tid) * 4 + st] = (float)v;
    }
    __syncthreads();

    // ---- register-local update: r_new = (ah+al) - E[idx]; loss += r_new^2;
    //      st<3 -> re-split into ah/al; st==3 -> x_q = x - r_new
    #pragma unroll
    for (int rt = 0; rt < 2; rt++) {
      int row = wv * 32 + rt * 16 + (lane & 15);
      int kidx = idxsW[row] & 1023;
      int d0b = (lane >> 4) * 8;
      #pragma unroll
      for (int kt = 0; kt < 4; kt++) {
        int d0 = d0b + kt * 32;
        const float* ep = Eq + (size_t)kidx * DIM + d0;
        float4 e0 = *(const float4*)(ep);
        float4 e1 = *(const float4*)(ep + 4);
        float e8[8] = {e0.x, e0.y, e0.z, e0.w, e1.x, e1.y, e1.z, e1.w};
        float r8[8];
        #pragma unroll
        for (int j = 0; j < 8; j++) {
          r8[j] = ((float)ah[rt][kt][j] + (float)al[rt][kt][j]) - e8[j];
          lsum = fmaf(r8[j], r8[j], lsum);
        }
        if (st < QST - 1) {
          #pragma unroll
          for (int j = 0; j < 8; j++) {
            _Float16 hh = (_Float16)r8[j];
            ah[rt][kt][j] = hh;
            al[rt][kt][j] = (_Float16)(r8[j] - (float)hh);
          }
        } else {
          const float* xp = x + (rowbase + row) * (size_t)DIM + d0;
          float4 xf0 = *(const float4*)(xp);
          float4 xf1 = *(const float4*)(xp + 4);
          float* op = xq + (rowbase + row) * (size_t)DIM + d0;
          *(float4*)(op)     = make_float4(xf0.x - r8[0], xf0.y - r8[1],
                                           xf0.z - r8[2], xf0.w - r8[3]);
          *(float4*)(op + 4) = make_float4(xf1.x - r8[4], xf1.y - r8[5],
                                           xf1.z - r8[6], xf1.w - r8[7]);
        }
      }
    }
  }

  // ---- block loss reduce -> lpart[block]
  #pragma unroll
  for (int m = 1; m < 64; m <<= 1) lsum += __shfl_xor(lsum, m, 64);
  if (lane == 0) redf[wv] = lsum;
  __syncthreads();
  if (tid == 0) lpart[blockIdx.x] = redf[0] + redf[1] + redf[2] + redf[3];
}

__global__ void k_loss(const float* __restrict__ part, float* __restrict__ o) {
  __shared__ float red[4];
  int tid = threadIdx.x;
  float s = 0.f;
  for (int i = tid; i < N_ROWS / BM; i += PNTH) s += part[i];
  #pragma unroll
  for (int m = 1; m < 64; m <<= 1) s += __shfl_xor(s, m, 64);
  if ((tid & 63) == 0) red[tid >> 6] = s;
  __syncthreads();
  if (tid == 0)
    o[0] = (red[0] + red[1] + red[2] + red[3]) *
           (1.25f / ((float)QST * (float)N_ROWS * (float)DIM));
}

extern "C" void kernel_launch(void* const* d_in, const int* in_sizes, int n_in,
                              void* d_out, int out_size, void* d_ws, size_t ws_size,
                              hipStream_t stream) {
  const float* x  = (const float*)d_in[0];
  const float* cb = (const float*)d_in[1];
  float* out = (float*)d_out;
  float* ws  = (float*)d_ws;

  double*   cvec64 = (double*)ws;                           // Q*K fp64 ||E||^2
  float*    cvec32 = (float*)(cvec64 + (size_t)QST * KC);
  float*    part   = cvec32 + (size_t)QST * KC;             // 1024 loss partials
  _Float16* packB  = (_Float16*)(part + (size_t)(N_ROWS / BM)); // 2 MB frags

  float* out_loss = out + (size_t)N_ROWS * DIM;
  float* out_idx  = out_loss + 1;

  k_prep<<<(QST * KC + PNTH - 1) / PNTH, PNTH, 0, stream>>>(cb, cvec64, cvec32, packB);

  k_fused<<<N_ROWS / BM, NTH, 0, stream>>>(x, out, cb, cvec64, cvec32, packB,
                                           out_idx, part);

  k_loss<<<1, PNTH, 0, stream>>>(part, out_loss);
}